// Round 5
// baseline (453.709 us; speedup 1.0000x reference)
//
#include <hip/hip_runtime.h>
#include <hip/hip_fp16.h>
#include <cstdint>
#include <cstddef>

#define N_NODES 100000
#define N_EDGES 1600000
#define BSH 6
#define BNODES 64
#define NB 1563          // ceil(100000/64)
#define CHUNK 2048

typedef _Float16 f16x8 __attribute__((ext_vector_type(8)));
typedef float f32x4 __attribute__((ext_vector_type(4)));

// ---------------- fp16 helpers ----------------

__device__ __forceinline__ float h2f(ushort u) {
    __half_raw r;
    r.x = u;
    return __half2float(__half(r));
}

__device__ __forceinline__ ushort f2h(float f) {
    __half h = __float2half(f);
    return static_cast<__half_raw>(h).x;
}

// ---------------- bucket binning (replaces per-node CSR) ----------------

__global__ void bucket_count(const int* __restrict__ dst, int* __restrict__ bcnt, int E) {
    __shared__ int lh[NB];
    for (int i = threadIdx.x; i < NB; i += 256) lh[i] = 0;
    __syncthreads();
    for (int e = blockIdx.x * blockDim.x + threadIdx.x; e < E; e += gridDim.x * blockDim.x)
        atomicAdd(&lh[dst[e] >> BSH], 1);
    __syncthreads();
    for (int i = threadIdx.x; i < NB; i += 256) {
        int v = lh[i];
        if (v) atomicAdd(&bcnt[i], v);
    }
}

// single-block exclusive scan over NB (<= 2048) elements
__global__ void scan_buckets(const int* __restrict__ bcnt, int* __restrict__ boffs) {
    __shared__ int sdata[256];
    int tid = threadIdx.x;
    int v[8];
    int s = 0;
#pragma unroll
    for (int i = 0; i < 8; i++) {
        int idx = tid * 8 + i;
        v[i] = (idx < NB) ? bcnt[idx] : 0;
        s += v[i];
    }
    sdata[tid] = s;
    __syncthreads();
    int acc = s;
    for (int off = 1; off < 256; off <<= 1) {
        int t = (tid >= off) ? sdata[tid - off] : 0;
        __syncthreads();
        acc += t;
        sdata[tid] = acc;
        __syncthreads();
    }
    int excl = acc - s;
#pragma unroll
    for (int i = 0; i < 8; i++) {
        int idx = tid * 8 + i;
        if (idx < NB) boffs[idx] = excl;
        excl += v[i];
    }
}

// scatter edges into bucket regions as packed (dstLocal<<17 | src)
__global__ void bucket_scatter(const int* __restrict__ src, const int* __restrict__ dst,
                               const int* __restrict__ boffs, int* __restrict__ gcur,
                               uint* __restrict__ bedges, int E) {
    __shared__ int lh[NB];
    __shared__ int lbase[NB];
    int nwg = gridDim.x;
    int chunk = (E + nwg - 1) / nwg;
    int e0 = blockIdx.x * chunk;
    int e1 = e0 + chunk;
    if (e1 > E) e1 = E;
    for (int i = threadIdx.x; i < NB; i += 256) lh[i] = 0;
    __syncthreads();
    for (int e = e0 + threadIdx.x; e < e1; e += 256)
        atomicAdd(&lh[dst[e] >> BSH], 1);
    __syncthreads();
    for (int i = threadIdx.x; i < NB; i += 256) {
        int v = lh[i];
        lbase[i] = v ? (boffs[i] + atomicAdd(&gcur[i], v)) : 0;
    }
    __syncthreads();
    for (int i = threadIdx.x; i < NB; i += 256) lh[i] = 0;  // reuse as local cursor
    __syncthreads();
    for (int e = e0 + threadIdx.x; e < e1; e += 256) {
        int d = dst[e];
        int b = d >> BSH;
        int r = atomicAdd(&lh[b], 1);
        bedges[lbase[b] + r] = ((uint)(d & (BNODES - 1)) << 17) | (uint)src[e];
    }
}

// ---------------- bucketed mean aggregation ----------------
// One workgroup per bucket (64 nodes). Per 2048-edge chunk: LDS counting-sort
// by dstLocal, then wave w accumulates nodes [w*16, w*16+16) in registers
// (lane covers channels {2l, 2l+1}). fp16 gather, fp32 accum, fp16 out.

__global__ __launch_bounds__(256) void aggregate_bucket(
        const ushort* __restrict__ F, const uint* __restrict__ bedges,
        const int* __restrict__ boffs, const int* __restrict__ bcnt,
        ushort* __restrict__ out, int n) {
    int b = blockIdx.x;
    int beg = boffs[b];
    int m = bcnt[b];
    int node0 = b << BSH;
    int nNodes = n - node0;
    if (nNodes > BNODES) nNodes = BNODES;
    __shared__ uint ls[CHUNK];
    __shared__ int lh[BNODES];
    __shared__ int lofs[BNODES];
    __shared__ int pcnt[BNODES];
    int wid = threadIdx.x >> 6;
    int lane = threadIdx.x & 63;

    float2 acc[16];
#pragma unroll
    for (int i = 0; i < 16; i++) acc[i] = make_float2(0.f, 0.f);
    if (threadIdx.x < BNODES) pcnt[threadIdx.x] = 0;

    for (int base = 0; base < m; base += CHUNK) {
        int mm = m - base;
        if (mm > CHUNK) mm = CHUNK;
        __syncthreads();
        if (threadIdx.x < BNODES) lh[threadIdx.x] = 0;
        __syncthreads();
        for (int i = threadIdx.x; i < mm; i += 256)
            atomicAdd(&lh[bedges[beg + base + i] >> 17], 1);
        __syncthreads();
        if (threadIdx.x < BNODES) {
            int v = lh[threadIdx.x];
            int s = v;
#pragma unroll
            for (int off = 1; off < 64; off <<= 1) {
                int t = __shfl_up(s, off);
                if (lane >= off) s += t;
            }
            lofs[threadIdx.x] = s - v;   // exclusive
            pcnt[threadIdx.x] += v;
            lh[threadIdx.x] = 0;         // reuse as cursor
        }
        __syncthreads();
        for (int i = threadIdx.x; i < mm; i += 256) {
            uint p = bedges[beg + base + i];
            int k = p >> 17;
            int r = atomicAdd(&lh[k], 1);
            ls[lofs[k] + r] = p;
        }
        __syncthreads();
#pragma unroll
        for (int ki = 0; ki < 16; ki++) {
            int k = wid * 16 + ki;
            int s0 = lofs[k];
            int ck = lh[k];
            int j = 0;
            for (; j + 4 <= ck; j += 4) {
                uint p0 = ls[s0 + j + 0] & 0x1FFFFu;
                uint p1 = ls[s0 + j + 1] & 0x1FFFFu;
                uint p2 = ls[s0 + j + 2] & 0x1FFFFu;
                uint p3 = ls[s0 + j + 3] & 0x1FFFFu;
                uint v0 = *reinterpret_cast<const uint*>(F + (size_t)p0 * 128 + lane * 2);
                uint v1 = *reinterpret_cast<const uint*>(F + (size_t)p1 * 128 + lane * 2);
                uint v2 = *reinterpret_cast<const uint*>(F + (size_t)p2 * 128 + lane * 2);
                uint v3 = *reinterpret_cast<const uint*>(F + (size_t)p3 * 128 + lane * 2);
                acc[ki].x += h2f((ushort)(v0 & 0xffff)) + h2f((ushort)(v1 & 0xffff)) +
                             h2f((ushort)(v2 & 0xffff)) + h2f((ushort)(v3 & 0xffff));
                acc[ki].y += h2f((ushort)(v0 >> 16)) + h2f((ushort)(v1 >> 16)) +
                             h2f((ushort)(v2 >> 16)) + h2f((ushort)(v3 >> 16));
            }
            for (; j < ck; j++) {
                uint p = ls[s0 + j] & 0x1FFFFu;
                uint v = *reinterpret_cast<const uint*>(F + (size_t)p * 128 + lane * 2);
                acc[ki].x += h2f((ushort)(v & 0xffff));
                acc[ki].y += h2f((ushort)(v >> 16));
            }
        }
    }
    __syncthreads();
#pragma unroll
    for (int ki = 0; ki < 16; ki++) {
        int k = wid * 16 + ki;
        if (k < nNodes) {
            float inv = 1.0f / fmaxf((float)pcnt[k], 1.0f);
            uint o = (uint)f2h(acc[ki].x * inv) | ((uint)f2h(acc[ki].y * inv) << 16);
            *reinterpret_cast<uint*>(out + (size_t)(node0 + k) * 128 + lane * 2) = o;
        }
    }
}

// ---------------- cast fp32 -> fp16 table ----------------

__global__ void cast_f32_f16(const float* __restrict__ in, ushort* __restrict__ out, int n4) {
    int i = blockIdx.x * blockDim.x + threadIdx.x;
    if (i < n4) {
        float4 v = reinterpret_cast<const float4*>(in)[i];
        ushort4 o;
        o.x = f2h(v.x);
        o.y = f2h(v.y);
        o.z = f2h(v.z);
        o.w = f2h(v.w);
        reinterpret_cast<ushort4*>(out)[i] = o;
    }
}

// ---------------- transpose-cast weights: W[K][C] f32 -> WT[C][K] f16 ----------------

__global__ void transpose_cast(const float* __restrict__ W, ushort* __restrict__ WT,
                               int K, int C) {
    int idx = blockIdx.x * blockDim.x + threadIdx.x;
    if (idx < K * C) {
        int k = idx / C, c = idx % C;
        WT[(size_t)c * K + k] = f2h(W[idx]);
    }
}

// ---------------- MFMA fp16 GEMM, fp32 accumulate ----------------

template <int NFRAG, bool HAS_A2, bool RELU, bool WF32, bool WF16>
__global__ __launch_bounds__(256) void mfma_gemm(const ushort* __restrict__ A1,
                                                 const ushort* __restrict__ B1T,
                                                 const ushort* __restrict__ A2,
                                                 const ushort* __restrict__ B2T,
                                                 const float* __restrict__ bias,
                                                 float* __restrict__ Cf,
                                                 ushort* __restrict__ Ch, int n) {
    constexpr int NC = NFRAG * 16;
    int wid = threadIdx.x >> 6;
    int lane = threadIdx.x & 63;
    int row0 = blockIdx.x * 128 + wid * 32;
    int fr = lane & 15;
    int ko = (lane >> 4) * 8;

    f32x4 acc[2][NFRAG];
#pragma unroll
    for (int m = 0; m < 2; m++)
#pragma unroll
        for (int nf = 0; nf < NFRAG; nf++) acc[m][nf] = (f32x4)0.f;

    const int nseg = HAS_A2 ? 2 : 1;
    for (int seg = 0; seg < nseg; ++seg) {
        const ushort* A = seg ? A2 : A1;
        const ushort* BT = seg ? B2T : B1T;
#pragma unroll
        for (int k0 = 0; k0 < 128; k0 += 32) {
            f16x8 av[2];
#pragma unroll
            for (int m = 0; m < 2; m++) {
                int row = row0 + m * 16 + fr;
                if (row >= n) row = n - 1;
                av[m] = *reinterpret_cast<const f16x8*>(A + (size_t)row * 128 + k0 + ko);
            }
            f16x8 bv[NFRAG];
#pragma unroll
            for (int nf = 0; nf < NFRAG; nf++)
                bv[nf] = *reinterpret_cast<const f16x8*>(BT + (size_t)(nf * 16 + fr) * 128 + k0 + ko);
#pragma unroll
            for (int m = 0; m < 2; m++)
#pragma unroll
                for (int nf = 0; nf < NFRAG; nf++)
                    acc[m][nf] = __builtin_amdgcn_mfma_f32_16x16x32_f16(av[m], bv[nf], acc[m][nf], 0, 0, 0);
        }
    }

    int crow = (lane >> 4) * 4;
    int ccol = lane & 15;
    float bv[NFRAG];
#pragma unroll
    for (int nf = 0; nf < NFRAG; nf++) bv[nf] = bias[nf * 16 + ccol];

#pragma unroll
    for (int m = 0; m < 2; m++) {
#pragma unroll
        for (int reg = 0; reg < 4; reg++) {
            int grow = row0 + m * 16 + crow + reg;
            if (grow < n) {
#pragma unroll
                for (int nf = 0; nf < NFRAG; nf++) {
                    float v = acc[m][nf][reg] + bv[nf];
                    if (RELU) v = fmaxf(v, 0.f);
                    if (WF32) Cf[(size_t)grow * NC + nf * 16 + ccol] = v;
                    if (WF16) Ch[(size_t)grow * NC + nf * 16 + ccol] = f2h(v);
                }
            }
        }
    }
}

// ---------------- in-place row L2 normalize ----------------

__global__ void normalize_rows(float* __restrict__ emb, int n) {
    int w = (blockIdx.x * blockDim.x + threadIdx.x) >> 6;
    int lane = threadIdx.x & 63;
    if (w >= n) return;
    float2 v = *reinterpret_cast<float2*>(emb + (size_t)w * 128 + lane * 2);
    float ss = v.x * v.x + v.y * v.y;
    for (int off = 1; off < 64; off <<= 1) ss += __shfl_xor(ss, off);
    float norm = sqrtf(ss);
    float inv = 1.0f / fmaxf(norm, 1e-12f);
    v.x *= inv;
    v.y *= inv;
    *reinterpret_cast<float2*>(emb + (size_t)w * 128 + lane * 2) = v;
}

// ---------------- launch ----------------

extern "C" void kernel_launch(void* const* d_in, const int* in_sizes, int n_in,
                              void* d_out, int out_size, void* d_ws, size_t ws_size,
                              hipStream_t stream) {
    const float* x   = (const float*)d_in[0];
    const int*   ei  = (const int*)d_in[1];
    const float* W1l = (const float*)d_in[2];
    const float* b1  = (const float*)d_in[3];
    const float* W1r = (const float*)d_in[4];
    const float* W2l = (const float*)d_in[5];
    const float* b2  = (const float*)d_in[6];
    const float* W2r = (const float*)d_in[7];
    const float* Wm  = (const float*)d_in[8];
    const float* bm  = (const float*)d_in[9];

    const int N = N_NODES, E = N_EDGES;
    const int* src = ei;
    const int* dst = ei + E;

    char* ws = (char*)d_ws;
    int* bcnt  = (int*)ws;  ws += sizeof(int) * NB;
    int* boffs = (int*)ws;  ws += sizeof(int) * NB;
    int* gcur  = (int*)ws;  ws += sizeof(int) * NB;
    uintptr_t p0 = ((uintptr_t)ws + 255) & ~(uintptr_t)255;
    uint* bedges = (uint*)p0;
    uintptr_t p1 = ((uintptr_t)(bedges + N_EDGES) + 255) & ~(uintptr_t)255;
    ushort* mean_f16 = (ushort*)p1;                 // N*128 fp16
    ushort* x_f16    = mean_f16 + (size_t)N * 128;
    ushort* h_f16    = x_f16 + (size_t)N * 128;
    ushort* emb_f16  = h_f16 + (size_t)N * 128;
    ushort* W1lT     = emb_f16 + (size_t)N * 128;   // [128][128] fp16
    ushort* W1rT     = W1lT + 128 * 128;
    ushort* W2lT     = W1rT + 128 * 128;
    ushort* W2rT     = W2lT + 128 * 128;
    ushort* WmT      = W2rT + 128 * 128;            // [64][128] fp16

    float* outp = (float*)d_out;            // N x 64
    float* emb  = outp + (size_t)N * 64;    // N x 128

    hipMemsetAsync(bcnt, 0, sizeof(int) * NB, stream);
    hipMemsetAsync(gcur, 0, sizeof(int) * NB, stream);

    bucket_count<<<128, 256, 0, stream>>>(dst, bcnt, E);
    scan_buckets<<<1, 256, 0, stream>>>(bcnt, boffs);
    bucket_scatter<<<64, 256, 0, stream>>>(src, dst, boffs, gcur, bedges, E);

    int n4 = N * 128 / 4;
    cast_f32_f16<<<(n4 + 255) / 256, 256, 0, stream>>>(x, x_f16, n4);
    transpose_cast<<<(128 * 128 + 255) / 256, 256, 0, stream>>>(W1l, W1lT, 128, 128);
    transpose_cast<<<(128 * 128 + 255) / 256, 256, 0, stream>>>(W1r, W1rT, 128, 128);
    transpose_cast<<<(128 * 128 + 255) / 256, 256, 0, stream>>>(W2l, W2lT, 128, 128);
    transpose_cast<<<(128 * 128 + 255) / 256, 256, 0, stream>>>(W2r, W2rT, 128, 128);
    transpose_cast<<<(128 * 64 + 255) / 256, 256, 0, stream>>>(Wm, WmT, 128, 64);

    int gblk = (N + 127) / 128;  // 782

    // Layer 1: mean = agg(x_f16); h_f16 = relu(mean@W1l + x@W1r + b1)
    aggregate_bucket<<<NB, 256, 0, stream>>>(x_f16, bedges, boffs, bcnt, mean_f16, N);
    mfma_gemm<8, true, true, false, true><<<gblk, 256, 0, stream>>>(
        mean_f16, W1lT, x_f16, W1rT, b1, nullptr, h_f16, N);

    // Layer 2: mean = agg(h_f16); emb = mean@W2l + h@W2r + b2  (fp32 + fp16 shadow)
    aggregate_bucket<<<NB, 256, 0, stream>>>(h_f16, bedges, boffs, bcnt, mean_f16, N);
    mfma_gemm<8, true, false, true, true><<<gblk, 256, 0, stream>>>(
        mean_f16, W2lT, h_f16, W2rT, b2, emb, emb_f16, N);

    // out = emb @ Wm + bm
    mfma_gemm<4, false, false, true, false><<<gblk, 256, 0, stream>>>(
        emb_f16, WmT, nullptr, nullptr, bm, outp, nullptr, N);

    // emb_n = emb / max(||emb||, 1e-12)  (in place)
    normalize_rows<<<(N + 3) / 4, 256, 0, stream>>>(emb, N);
}

// Round 6
// 377.890 us; speedup vs baseline: 1.2006x; 1.2006x over previous
//
#include <hip/hip_runtime.h>
#include <hip/hip_fp16.h>
#include <cstdint>
#include <cstddef>

#define N_NODES 100000
#define N_EDGES 1600000
#define BSH 6
#define BNODES 64
#define NB 1563          // ceil(100000/64)
#define CHUNK 2048

typedef _Float16 f16x8 __attribute__((ext_vector_type(8)));
typedef float f32x4 __attribute__((ext_vector_type(4)));

// ---------------- fp16 helpers ----------------

__device__ __forceinline__ float h2f(ushort u) {
    __half_raw r;
    r.x = u;
    return __half2float(__half(r));
}

__device__ __forceinline__ ushort f2h(float f) {
    __half h = __float2half(f);
    return static_cast<__half_raw>(h).x;
}

// ---------------- bucket binning (replaces per-node CSR) ----------------

__global__ void bucket_count(const int* __restrict__ dst, int* __restrict__ bcnt, int E) {
    __shared__ int lh[NB];
    for (int i = threadIdx.x; i < NB; i += 256) lh[i] = 0;
    __syncthreads();
    for (int e = blockIdx.x * blockDim.x + threadIdx.x; e < E; e += gridDim.x * blockDim.x)
        atomicAdd(&lh[dst[e] >> BSH], 1);
    __syncthreads();
    for (int i = threadIdx.x; i < NB; i += 256) {
        int v = lh[i];
        if (v) atomicAdd(&bcnt[i], v);
    }
}

// single-block exclusive scan over NB (<= 2048) elements
__global__ void scan_buckets(const int* __restrict__ bcnt, int* __restrict__ boffs) {
    __shared__ int sdata[256];
    int tid = threadIdx.x;
    int v[8];
    int s = 0;
#pragma unroll
    for (int i = 0; i < 8; i++) {
        int idx = tid * 8 + i;
        v[i] = (idx < NB) ? bcnt[idx] : 0;
        s += v[i];
    }
    sdata[tid] = s;
    __syncthreads();
    int acc = s;
    for (int off = 1; off < 256; off <<= 1) {
        int t = (tid >= off) ? sdata[tid - off] : 0;
        __syncthreads();
        acc += t;
        sdata[tid] = acc;
        __syncthreads();
    }
    int excl = acc - s;
#pragma unroll
    for (int i = 0; i < 8; i++) {
        int idx = tid * 8 + i;
        if (idx < NB) boffs[idx] = excl;
        excl += v[i];
    }
}

// scatter edges into bucket regions as packed (dstLocal<<17 | src)
__global__ void bucket_scatter(const int* __restrict__ src, const int* __restrict__ dst,
                               const int* __restrict__ boffs, int* __restrict__ gcur,
                               uint* __restrict__ bedges, int E) {
    __shared__ int lh[NB];
    __shared__ int lbase[NB];
    int nwg = gridDim.x;
    int chunk = (E + nwg - 1) / nwg;
    int e0 = blockIdx.x * chunk;
    int e1 = e0 + chunk;
    if (e1 > E) e1 = E;
    for (int i = threadIdx.x; i < NB; i += 256) lh[i] = 0;
    __syncthreads();
    for (int e = e0 + threadIdx.x; e < e1; e += 256)
        atomicAdd(&lh[dst[e] >> BSH], 1);
    __syncthreads();
    for (int i = threadIdx.x; i < NB; i += 256) {
        int v = lh[i];
        lbase[i] = v ? (boffs[i] + atomicAdd(&gcur[i], v)) : 0;
    }
    __syncthreads();
    for (int i = threadIdx.x; i < NB; i += 256) lh[i] = 0;  // reuse as local cursor
    __syncthreads();
    // 4 independent edges in flight per lane
    int e = e0 + threadIdx.x;
#pragma unroll 1
    for (; e + 3 * 256 < e1; e += 4 * 256) {
        int d0 = dst[e + 0 * 256], s0 = src[e + 0 * 256];
        int d1 = dst[e + 1 * 256], s1 = src[e + 1 * 256];
        int d2 = dst[e + 2 * 256], s2 = src[e + 2 * 256];
        int d3 = dst[e + 3 * 256], s3 = src[e + 3 * 256];
        int b0 = d0 >> BSH, b1 = d1 >> BSH, b2 = d2 >> BSH, b3 = d3 >> BSH;
        int r0 = atomicAdd(&lh[b0], 1);
        int r1 = atomicAdd(&lh[b1], 1);
        int r2 = atomicAdd(&lh[b2], 1);
        int r3 = atomicAdd(&lh[b3], 1);
        bedges[lbase[b0] + r0] = ((uint)(d0 & (BNODES - 1)) << 17) | (uint)s0;
        bedges[lbase[b1] + r1] = ((uint)(d1 & (BNODES - 1)) << 17) | (uint)s1;
        bedges[lbase[b2] + r2] = ((uint)(d2 & (BNODES - 1)) << 17) | (uint)s2;
        bedges[lbase[b3] + r3] = ((uint)(d3 & (BNODES - 1)) << 17) | (uint)s3;
    }
    for (; e < e1; e += 256) {
        int d = dst[e];
        int b = d >> BSH;
        int r = atomicAdd(&lh[b], 1);
        bedges[lbase[b] + r] = ((uint)(d & (BNODES - 1)) << 17) | (uint)src[e];
    }
}

// ---------------- bucketed mean aggregation ----------------
// One workgroup per bucket (64 nodes). Per 2048-edge chunk: LDS counting-sort
// by dstLocal, then wave w accumulates nodes [w*16, w*16+16) in registers
// (lane covers channels {2l, 2l+1}). fp16 gather, fp32 accum, fp16 out.

__global__ __launch_bounds__(256) void aggregate_bucket(
        const ushort* __restrict__ F, const uint* __restrict__ bedges,
        const int* __restrict__ boffs, const int* __restrict__ bcnt,
        ushort* __restrict__ out, int n) {
    int b = blockIdx.x;
    int beg = boffs[b];
    int m = bcnt[b];
    int node0 = b << BSH;
    int nNodes = n - node0;
    if (nNodes > BNODES) nNodes = BNODES;
    __shared__ uint ls[CHUNK];
    __shared__ int lh[BNODES];
    __shared__ int lofs[BNODES];
    __shared__ int pcnt[BNODES];
    int wid = threadIdx.x >> 6;
    int lane = threadIdx.x & 63;

    float2 acc[16];
#pragma unroll
    for (int i = 0; i < 16; i++) acc[i] = make_float2(0.f, 0.f);
    if (threadIdx.x < BNODES) pcnt[threadIdx.x] = 0;

    for (int base = 0; base < m; base += CHUNK) {
        int mm = m - base;
        if (mm > CHUNK) mm = CHUNK;
        __syncthreads();
        if (threadIdx.x < BNODES) lh[threadIdx.x] = 0;
        __syncthreads();
        for (int i = threadIdx.x; i < mm; i += 256)
            atomicAdd(&lh[bedges[beg + base + i] >> 17], 1);
        __syncthreads();
        if (threadIdx.x < BNODES) {
            int v = lh[threadIdx.x];
            int s = v;
#pragma unroll
            for (int off = 1; off < 64; off <<= 1) {
                int t = __shfl_up(s, off);
                if (lane >= off) s += t;
            }
            lofs[threadIdx.x] = s - v;   // exclusive
            pcnt[threadIdx.x] += v;
            lh[threadIdx.x] = 0;         // reuse as cursor
        }
        __syncthreads();
        for (int i = threadIdx.x; i < mm; i += 256) {
            uint p = bedges[beg + base + i];
            int k = p >> 17;
            int r = atomicAdd(&lh[k], 1);
            ls[lofs[k] + r] = p;
        }
        __syncthreads();
#pragma unroll
        for (int ki = 0; ki < 16; ki++) {
            int k = wid * 16 + ki;
            int s0 = lofs[k];
            int ck = lh[k];
            int j = 0;
            for (; j + 4 <= ck; j += 4) {
                uint p0 = ls[s0 + j + 0] & 0x1FFFFu;
                uint p1 = ls[s0 + j + 1] & 0x1FFFFu;
                uint p2 = ls[s0 + j + 2] & 0x1FFFFu;
                uint p3 = ls[s0 + j + 3] & 0x1FFFFu;
                uint v0 = *reinterpret_cast<const uint*>(F + (size_t)p0 * 128 + lane * 2);
                uint v1 = *reinterpret_cast<const uint*>(F + (size_t)p1 * 128 + lane * 2);
                uint v2 = *reinterpret_cast<const uint*>(F + (size_t)p2 * 128 + lane * 2);
                uint v3 = *reinterpret_cast<const uint*>(F + (size_t)p3 * 128 + lane * 2);
                acc[ki].x += h2f((ushort)(v0 & 0xffff)) + h2f((ushort)(v1 & 0xffff)) +
                             h2f((ushort)(v2 & 0xffff)) + h2f((ushort)(v3 & 0xffff));
                acc[ki].y += h2f((ushort)(v0 >> 16)) + h2f((ushort)(v1 >> 16)) +
                             h2f((ushort)(v2 >> 16)) + h2f((ushort)(v3 >> 16));
            }
            for (; j < ck; j++) {
                uint p = ls[s0 + j] & 0x1FFFFu;
                uint v = *reinterpret_cast<const uint*>(F + (size_t)p * 128 + lane * 2);
                acc[ki].x += h2f((ushort)(v & 0xffff));
                acc[ki].y += h2f((ushort)(v >> 16));
            }
        }
    }
    __syncthreads();
#pragma unroll
    for (int ki = 0; ki < 16; ki++) {
        int k = wid * 16 + ki;
        if (k < nNodes) {
            float inv = 1.0f / fmaxf((float)pcnt[k], 1.0f);
            uint o = (uint)f2h(acc[ki].x * inv) | ((uint)f2h(acc[ki].y * inv) << 16);
            *reinterpret_cast<uint*>(out + (size_t)(node0 + k) * 128 + lane * 2) = o;
        }
    }
}

// ---------------- cast fp32 -> fp16 table ----------------

__global__ void cast_f32_f16(const float* __restrict__ in, ushort* __restrict__ out, int n4) {
    int i = blockIdx.x * blockDim.x + threadIdx.x;
    if (i < n4) {
        float4 v = reinterpret_cast<const float4*>(in)[i];
        ushort4 o;
        o.x = f2h(v.x);
        o.y = f2h(v.y);
        o.z = f2h(v.z);
        o.w = f2h(v.w);
        reinterpret_cast<ushort4*>(out)[i] = o;
    }
}

// ---------------- transpose-cast weights: W[K][C] f32 -> WT[C][K] f16 ----------------

__global__ void transpose_cast(const float* __restrict__ W, ushort* __restrict__ WT,
                               int K, int C) {
    int idx = blockIdx.x * blockDim.x + threadIdx.x;
    if (idx < K * C) {
        int k = idx / C, c = idx % C;
        WT[(size_t)c * K + k] = f2h(W[idx]);
    }
}

// ---------------- MFMA fp16 GEMM, fp32 accumulate ----------------

template <int NFRAG, bool HAS_A2, bool RELU, bool WF32, bool WF16>
__global__ __launch_bounds__(256) void mfma_gemm(const ushort* __restrict__ A1,
                                                 const ushort* __restrict__ B1T,
                                                 const ushort* __restrict__ A2,
                                                 const ushort* __restrict__ B2T,
                                                 const float* __restrict__ bias,
                                                 float* __restrict__ Cf,
                                                 ushort* __restrict__ Ch, int n) {
    constexpr int NC = NFRAG * 16;
    int wid = threadIdx.x >> 6;
    int lane = threadIdx.x & 63;
    int row0 = blockIdx.x * 128 + wid * 32;
    int fr = lane & 15;
    int ko = (lane >> 4) * 8;

    f32x4 acc[2][NFRAG];
#pragma unroll
    for (int m = 0; m < 2; m++)
#pragma unroll
        for (int nf = 0; nf < NFRAG; nf++) acc[m][nf] = (f32x4)0.f;

    const int nseg = HAS_A2 ? 2 : 1;
    for (int seg = 0; seg < nseg; ++seg) {
        const ushort* A = seg ? A2 : A1;
        const ushort* BT = seg ? B2T : B1T;
#pragma unroll
        for (int k0 = 0; k0 < 128; k0 += 32) {
            f16x8 av[2];
#pragma unroll
            for (int m = 0; m < 2; m++) {
                int row = row0 + m * 16 + fr;
                if (row >= n) row = n - 1;
                av[m] = *reinterpret_cast<const f16x8*>(A + (size_t)row * 128 + k0 + ko);
            }
            f16x8 bv[NFRAG];
#pragma unroll
            for (int nf = 0; nf < NFRAG; nf++)
                bv[nf] = *reinterpret_cast<const f16x8*>(BT + (size_t)(nf * 16 + fr) * 128 + k0 + ko);
#pragma unroll
            for (int m = 0; m < 2; m++)
#pragma unroll
                for (int nf = 0; nf < NFRAG; nf++)
                    acc[m][nf] = __builtin_amdgcn_mfma_f32_16x16x32_f16(av[m], bv[nf], acc[m][nf], 0, 0, 0);
        }
    }

    int crow = (lane >> 4) * 4;
    int ccol = lane & 15;
    float bv[NFRAG];
#pragma unroll
    for (int nf = 0; nf < NFRAG; nf++) bv[nf] = bias[nf * 16 + ccol];

#pragma unroll
    for (int m = 0; m < 2; m++) {
#pragma unroll
        for (int reg = 0; reg < 4; reg++) {
            int grow = row0 + m * 16 + crow + reg;
            if (grow < n) {
#pragma unroll
                for (int nf = 0; nf < NFRAG; nf++) {
                    float v = acc[m][nf][reg] + bv[nf];
                    if (RELU) v = fmaxf(v, 0.f);
                    if (WF32) Cf[(size_t)grow * NC + nf * 16 + ccol] = v;
                    if (WF16) Ch[(size_t)grow * NC + nf * 16 + ccol] = f2h(v);
                }
            }
        }
    }
}

// ---------------- in-place row L2 normalize ----------------

__global__ void normalize_rows(float* __restrict__ emb, int n) {
    int w = (blockIdx.x * blockDim.x + threadIdx.x) >> 6;
    int lane = threadIdx.x & 63;
    if (w >= n) return;
    float2 v = *reinterpret_cast<float2*>(emb + (size_t)w * 128 + lane * 2);
    float ss = v.x * v.x + v.y * v.y;
    for (int off = 1; off < 64; off <<= 1) ss += __shfl_xor(ss, off);
    float norm = sqrtf(ss);
    float inv = 1.0f / fmaxf(norm, 1e-12f);
    v.x *= inv;
    v.y *= inv;
    *reinterpret_cast<float2*>(emb + (size_t)w * 128 + lane * 2) = v;
}

// ---------------- launch ----------------

extern "C" void kernel_launch(void* const* d_in, const int* in_sizes, int n_in,
                              void* d_out, int out_size, void* d_ws, size_t ws_size,
                              hipStream_t stream) {
    const float* x   = (const float*)d_in[0];
    const int*   ei  = (const int*)d_in[1];
    const float* W1l = (const float*)d_in[2];
    const float* b1  = (const float*)d_in[3];
    const float* W1r = (const float*)d_in[4];
    const float* W2l = (const float*)d_in[5];
    const float* b2  = (const float*)d_in[6];
    const float* W2r = (const float*)d_in[7];
    const float* Wm  = (const float*)d_in[8];
    const float* bm  = (const float*)d_in[9];

    const int N = N_NODES, E = N_EDGES;
    const int* src = ei;
    const int* dst = ei + E;

    char* ws = (char*)d_ws;
    int* bcnt  = (int*)ws;  ws += sizeof(int) * NB;
    int* boffs = (int*)ws;  ws += sizeof(int) * NB;
    int* gcur  = (int*)ws;  ws += sizeof(int) * NB;
    uintptr_t p0 = ((uintptr_t)ws + 255) & ~(uintptr_t)255;
    uint* bedges = (uint*)p0;
    uintptr_t p1 = ((uintptr_t)(bedges + N_EDGES) + 255) & ~(uintptr_t)255;
    ushort* mean_f16 = (ushort*)p1;                 // N*128 fp16
    ushort* x_f16    = mean_f16 + (size_t)N * 128;
    ushort* h_f16    = x_f16 + (size_t)N * 128;
    ushort* emb_f16  = h_f16 + (size_t)N * 128;
    ushort* W1lT     = emb_f16 + (size_t)N * 128;   // [128][128] fp16
    ushort* W1rT     = W1lT + 128 * 128;
    ushort* W2lT     = W1rT + 128 * 128;
    ushort* W2rT     = W2lT + 128 * 128;
    ushort* WmT      = W2rT + 128 * 128;            // [64][128] fp16

    float* outp = (float*)d_out;            // N x 64
    float* emb  = outp + (size_t)N * 64;    // N x 128

    hipMemsetAsync(bcnt, 0, sizeof(int) * NB, stream);
    hipMemsetAsync(gcur, 0, sizeof(int) * NB, stream);

    bucket_count<<<256, 256, 0, stream>>>(dst, bcnt, E);
    scan_buckets<<<1, 256, 0, stream>>>(bcnt, boffs);
    bucket_scatter<<<256, 256, 0, stream>>>(src, dst, boffs, gcur, bedges, E);

    int n4 = N * 128 / 4;
    cast_f32_f16<<<(n4 + 255) / 256, 256, 0, stream>>>(x, x_f16, n4);
    transpose_cast<<<(128 * 128 + 255) / 256, 256, 0, stream>>>(W1l, W1lT, 128, 128);
    transpose_cast<<<(128 * 128 + 255) / 256, 256, 0, stream>>>(W1r, W1rT, 128, 128);
    transpose_cast<<<(128 * 128 + 255) / 256, 256, 0, stream>>>(W2l, W2lT, 128, 128);
    transpose_cast<<<(128 * 128 + 255) / 256, 256, 0, stream>>>(W2r, W2rT, 128, 128);
    transpose_cast<<<(128 * 64 + 255) / 256, 256, 0, stream>>>(Wm, WmT, 128, 64);

    int gblk = (N + 127) / 128;  // 782

    // Layer 1: mean = agg(x_f16); h_f16 = relu(mean@W1l + x@W1r + b1)
    aggregate_bucket<<<NB, 256, 0, stream>>>(x_f16, bedges, boffs, bcnt, mean_f16, N);
    mfma_gemm<8, true, true, false, true><<<gblk, 256, 0, stream>>>(
        mean_f16, W1lT, x_f16, W1rT, b1, nullptr, h_f16, N);

    // Layer 2: mean = agg(h_f16); emb = mean@W2l + h@W2r + b2  (fp32 + fp16 shadow)
    aggregate_bucket<<<NB, 256, 0, stream>>>(h_f16, bedges, boffs, bcnt, mean_f16, N);
    mfma_gemm<8, true, false, true, true><<<gblk, 256, 0, stream>>>(
        mean_f16, W2lT, h_f16, W2rT, b2, emb, emb_f16, N);

    // out = emb @ Wm + bm
    mfma_gemm<4, false, false, true, false><<<gblk, 256, 0, stream>>>(
        emb_f16, WmT, nullptr, nullptr, bm, outp, nullptr, N);

    // emb_n = emb / max(||emb||, 1e-12)  (in place)
    normalize_rows<<<(N + 3) / 4, 256, 0, stream>>>(emb, N);
}

// Round 7
// 337.652 us; speedup vs baseline: 1.3437x; 1.1192x over previous
//
#include <hip/hip_runtime.h>
#include <hip/hip_fp16.h>
#include <cstdint>
#include <cstddef>

#define N_NODES 100000
#define N_EDGES 1600000
#define BSH 6
#define BNODES 64
#define NB 1563          // ceil(100000/64)
#define CHUNK 2048

typedef _Float16 f16x8 __attribute__((ext_vector_type(8)));
typedef float f32x4 __attribute__((ext_vector_type(4)));

// ---------------- fp16 helpers ----------------

__device__ __forceinline__ float h2f(ushort u) {
    __half_raw r;
    r.x = u;
    return __half2float(__half(r));
}

__device__ __forceinline__ ushort f2h(float f) {
    __half h = __float2half(f);
    return static_cast<__half_raw>(h).x;
}

__device__ __forceinline__ void acc4(float4& a, uint2 v) {
    a.x += h2f((ushort)(v.x & 0xffff));
    a.y += h2f((ushort)(v.x >> 16));
    a.z += h2f((ushort)(v.y & 0xffff));
    a.w += h2f((ushort)(v.y >> 16));
}

// ---------------- bucket binning ----------------

__global__ void bucket_count(const int* __restrict__ dst, int* __restrict__ bcnt, int E) {
    __shared__ int lh[NB];
    for (int i = threadIdx.x; i < NB; i += 256) lh[i] = 0;
    __syncthreads();
    for (int e = blockIdx.x * blockDim.x + threadIdx.x; e < E; e += gridDim.x * blockDim.x)
        atomicAdd(&lh[dst[e] >> BSH], 1);
    __syncthreads();
    for (int i = threadIdx.x; i < NB; i += 256) {
        int v = lh[i];
        if (v) atomicAdd(&bcnt[i], v);
    }
}

// single-block exclusive scan over NB (<= 2048) elements
__global__ void scan_buckets(const int* __restrict__ bcnt, int* __restrict__ boffs) {
    __shared__ int sdata[256];
    int tid = threadIdx.x;
    int v[8];
    int s = 0;
#pragma unroll
    for (int i = 0; i < 8; i++) {
        int idx = tid * 8 + i;
        v[i] = (idx < NB) ? bcnt[idx] : 0;
        s += v[i];
    }
    sdata[tid] = s;
    __syncthreads();
    int acc = s;
    for (int off = 1; off < 256; off <<= 1) {
        int t = (tid >= off) ? sdata[tid - off] : 0;
        __syncthreads();
        acc += t;
        sdata[tid] = acc;
        __syncthreads();
    }
    int excl = acc - s;
#pragma unroll
    for (int i = 0; i < 8; i++) {
        int idx = tid * 8 + i;
        if (idx < NB) boffs[idx] = excl;
        excl += v[i];
    }
}

// scatter edges into bucket regions as packed (dstLocal<<17 | src)
__global__ void bucket_scatter(const int* __restrict__ src, const int* __restrict__ dst,
                               const int* __restrict__ boffs, int* __restrict__ gcur,
                               uint* __restrict__ bedges, int E) {
    __shared__ int lh[NB];
    __shared__ int lbase[NB];
    int nwg = gridDim.x;
    int chunk = (E + nwg - 1) / nwg;
    int e0 = blockIdx.x * chunk;
    int e1 = e0 + chunk;
    if (e1 > E) e1 = E;
    for (int i = threadIdx.x; i < NB; i += 256) lh[i] = 0;
    __syncthreads();
    for (int e = e0 + threadIdx.x; e < e1; e += 256)
        atomicAdd(&lh[dst[e] >> BSH], 1);
    __syncthreads();
    for (int i = threadIdx.x; i < NB; i += 256) {
        int v = lh[i];
        lbase[i] = v ? (boffs[i] + atomicAdd(&gcur[i], v)) : 0;
    }
    __syncthreads();
    for (int i = threadIdx.x; i < NB; i += 256) lh[i] = 0;  // reuse as local cursor
    __syncthreads();
    int e = e0 + threadIdx.x;
#pragma unroll 1
    for (; e + 3 * 256 < e1; e += 4 * 256) {
        int d0 = dst[e + 0 * 256], s0 = src[e + 0 * 256];
        int d1 = dst[e + 1 * 256], s1 = src[e + 1 * 256];
        int d2 = dst[e + 2 * 256], s2 = src[e + 2 * 256];
        int d3 = dst[e + 3 * 256], s3 = src[e + 3 * 256];
        int b0 = d0 >> BSH, b1 = d1 >> BSH, b2 = d2 >> BSH, b3 = d3 >> BSH;
        int r0 = atomicAdd(&lh[b0], 1);
        int r1 = atomicAdd(&lh[b1], 1);
        int r2 = atomicAdd(&lh[b2], 1);
        int r3 = atomicAdd(&lh[b3], 1);
        bedges[lbase[b0] + r0] = ((uint)(d0 & (BNODES - 1)) << 17) | (uint)s0;
        bedges[lbase[b1] + r1] = ((uint)(d1 & (BNODES - 1)) << 17) | (uint)s1;
        bedges[lbase[b2] + r2] = ((uint)(d2 & (BNODES - 1)) << 17) | (uint)s2;
        bedges[lbase[b3] + r3] = ((uint)(d3 & (BNODES - 1)) << 17) | (uint)s3;
    }
    for (; e < e1; e += 256) {
        int d = dst[e];
        int b = d >> BSH;
        int r = atomicAdd(&lh[b], 1);
        bedges[lbase[b] + r] = ((uint)(d & (BNODES - 1)) << 17) | (uint)src[e];
    }
}

// ---------------- bucketed mean aggregation (512 threads, 8 waves x 8 nodes) ----------------
// Per chunk: LDS counting-sort by dstLocal. Then wave w owns nodes [w*8, w*8+8);
// half-wave hw processes alternating edges, lane&31 covers 4 channels (uint2 = 8B),
// unroll 4 -> 8 independent row loads in flight per wave. Cross-half shfl merge at end.

__global__ __launch_bounds__(512) void aggregate_bucket(
        const ushort* __restrict__ F, const uint* __restrict__ bedges,
        const int* __restrict__ boffs, const int* __restrict__ bcnt,
        ushort* __restrict__ out, int n) {
    int b = blockIdx.x;
    int beg = boffs[b];
    int m = bcnt[b];
    int node0 = b << BSH;
    int nNodes = n - node0;
    if (nNodes > BNODES) nNodes = BNODES;
    __shared__ uint ls[CHUNK];
    __shared__ int lh[BNODES];
    __shared__ int lofs[BNODES];
    __shared__ int pcnt[BNODES];
    int tid = threadIdx.x;
    int wid = tid >> 6;     // 0..7
    int lane = tid & 63;
    int hw = lane >> 5;     // half-wave 0/1
    int cl = lane & 31;     // channels cl*4 .. cl*4+3

    float4 acc[8];
#pragma unroll
    for (int i = 0; i < 8; i++) acc[i] = make_float4(0.f, 0.f, 0.f, 0.f);
    if (tid < BNODES) pcnt[tid] = 0;

    for (int base = 0; base < m; base += CHUNK) {
        int mm = m - base;
        if (mm > CHUNK) mm = CHUNK;
        __syncthreads();
        if (tid < BNODES) lh[tid] = 0;
        __syncthreads();
        for (int i = tid; i < mm; i += 512)
            atomicAdd(&lh[bedges[beg + base + i] >> 17], 1);
        __syncthreads();
        if (tid < BNODES) {   // wave 0 only
            int v = lh[tid];
            int s = v;
#pragma unroll
            for (int off = 1; off < 64; off <<= 1) {
                int t = __shfl_up(s, off);
                if (lane >= off) s += t;
            }
            lofs[tid] = s - v;   // exclusive
            pcnt[tid] += v;
            lh[tid] = 0;         // reuse as cursor
        }
        __syncthreads();
        for (int i = tid; i < mm; i += 512) {
            uint p = bedges[beg + base + i];
            int k = p >> 17;
            int r = atomicAdd(&lh[k], 1);
            ls[lofs[k] + r] = p;
        }
        __syncthreads();
#pragma unroll
        for (int ki = 0; ki < 8; ki++) {
            int k = wid * 8 + ki;
            int s0 = lofs[k];
            int ck = lh[k];
            int j = hw;
            for (; j + 6 < ck; j += 8) {
                uint p0 = ls[s0 + j + 0] & 0x1FFFFu;
                uint p1 = ls[s0 + j + 2] & 0x1FFFFu;
                uint p2 = ls[s0 + j + 4] & 0x1FFFFu;
                uint p3 = ls[s0 + j + 6] & 0x1FFFFu;
                uint2 v0 = *reinterpret_cast<const uint2*>(F + (size_t)p0 * 128 + cl * 4);
                uint2 v1 = *reinterpret_cast<const uint2*>(F + (size_t)p1 * 128 + cl * 4);
                uint2 v2 = *reinterpret_cast<const uint2*>(F + (size_t)p2 * 128 + cl * 4);
                uint2 v3 = *reinterpret_cast<const uint2*>(F + (size_t)p3 * 128 + cl * 4);
                acc4(acc[ki], v0);
                acc4(acc[ki], v1);
                acc4(acc[ki], v2);
                acc4(acc[ki], v3);
            }
            for (; j < ck; j += 2) {
                uint p = ls[s0 + j] & 0x1FFFFu;
                uint2 v = *reinterpret_cast<const uint2*>(F + (size_t)p * 128 + cl * 4);
                acc4(acc[ki], v);
            }
        }
    }
    __syncthreads();
#pragma unroll
    for (int ki = 0; ki < 8; ki++) {
        acc[ki].x += __shfl_xor(acc[ki].x, 32);
        acc[ki].y += __shfl_xor(acc[ki].y, 32);
        acc[ki].z += __shfl_xor(acc[ki].z, 32);
        acc[ki].w += __shfl_xor(acc[ki].w, 32);
    }
    if (hw == 0) {
#pragma unroll
        for (int ki = 0; ki < 8; ki++) {
            int k = wid * 8 + ki;
            if (k < nNodes) {
                float inv = 1.0f / fmaxf((float)pcnt[k], 1.0f);
                uint2 o;
                o.x = (uint)f2h(acc[ki].x * inv) | ((uint)f2h(acc[ki].y * inv) << 16);
                o.y = (uint)f2h(acc[ki].z * inv) | ((uint)f2h(acc[ki].w * inv) << 16);
                *reinterpret_cast<uint2*>(out + (size_t)(node0 + k) * 128 + cl * 4) = o;
            }
        }
    }
}

// ---------------- cast fp32 -> fp16 table ----------------

__global__ void cast_f32_f16(const float* __restrict__ in, ushort* __restrict__ out, int n4) {
    int i = blockIdx.x * blockDim.x + threadIdx.x;
    if (i < n4) {
        float4 v = reinterpret_cast<const float4*>(in)[i];
        ushort4 o;
        o.x = f2h(v.x);
        o.y = f2h(v.y);
        o.z = f2h(v.z);
        o.w = f2h(v.w);
        reinterpret_cast<ushort4*>(out)[i] = o;
    }
}

// ---------------- transpose-cast weights: W[K][C] f32 -> WT[C][K] f16 ----------------

__global__ void transpose_cast(const float* __restrict__ W, ushort* __restrict__ WT,
                               int K, int C) {
    int idx = blockIdx.x * blockDim.x + threadIdx.x;
    if (idx < K * C) {
        int k = idx / C, c = idx % C;
        WT[(size_t)c * K + k] = f2h(W[idx]);
    }
}

// ---------------- MFMA fp16 GEMM (layer 1), fp16 output only ----------------

template <bool RELU>
__global__ __launch_bounds__(256) void mfma_gemm(const ushort* __restrict__ A1,
                                                 const ushort* __restrict__ B1T,
                                                 const ushort* __restrict__ A2,
                                                 const ushort* __restrict__ B2T,
                                                 const float* __restrict__ bias,
                                                 ushort* __restrict__ Ch, int n) {
    int wid = threadIdx.x >> 6;
    int lane = threadIdx.x & 63;
    int row0 = blockIdx.x * 128 + wid * 32;
    int fr = lane & 15;
    int ko = (lane >> 4) * 8;

    f32x4 acc[2][8];
#pragma unroll
    for (int m = 0; m < 2; m++)
#pragma unroll
        for (int nf = 0; nf < 8; nf++) acc[m][nf] = (f32x4)0.f;

    for (int seg = 0; seg < 2; ++seg) {
        const ushort* A = seg ? A2 : A1;
        const ushort* BT = seg ? B2T : B1T;
#pragma unroll
        for (int k0 = 0; k0 < 128; k0 += 32) {
            f16x8 av[2];
#pragma unroll
            for (int m = 0; m < 2; m++) {
                int row = row0 + m * 16 + fr;
                if (row >= n) row = n - 1;
                av[m] = *reinterpret_cast<const f16x8*>(A + (size_t)row * 128 + k0 + ko);
            }
            f16x8 bv[8];
#pragma unroll
            for (int nf = 0; nf < 8; nf++)
                bv[nf] = *reinterpret_cast<const f16x8*>(BT + (size_t)(nf * 16 + fr) * 128 + k0 + ko);
#pragma unroll
            for (int m = 0; m < 2; m++)
#pragma unroll
                for (int nf = 0; nf < 8; nf++)
                    acc[m][nf] = __builtin_amdgcn_mfma_f32_16x16x32_f16(av[m], bv[nf], acc[m][nf], 0, 0, 0);
        }
    }

    int crow = (lane >> 4) * 4;
    int ccol = lane & 15;
    float bv[8];
#pragma unroll
    for (int nf = 0; nf < 8; nf++) bv[nf] = bias[nf * 16 + ccol];

#pragma unroll
    for (int m = 0; m < 2; m++) {
#pragma unroll
        for (int reg = 0; reg < 4; reg++) {
            int grow = row0 + m * 16 + crow + reg;
            if (grow < n) {
#pragma unroll
                for (int nf = 0; nf < 8; nf++) {
                    float v = acc[m][nf][reg] + bv[nf];
                    if (RELU) v = fmaxf(v, 0.f);
                    Ch[(size_t)grow * 128 + nf * 16 + ccol] = f2h(v);
                }
            }
        }
    }
}

// ---------------- fused layer-2 GEMM + L2-normalize + output GEMM ----------------
// emb = mean@W2l + h@W2r + b2 (in registers); emb_n = emb/||emb|| -> d_out;
// emb_f16 tile staged in LDS; out = emb@Wm + bm -> d_out.

__global__ __launch_bounds__(256) void gemm2_fused(const ushort* __restrict__ A1,
                                                   const ushort* __restrict__ B1T,
                                                   const ushort* __restrict__ A2,
                                                   const ushort* __restrict__ B2T,
                                                   const float* __restrict__ bias,
                                                   const ushort* __restrict__ WmT,
                                                   const float* __restrict__ bm,
                                                   float* __restrict__ outp,
                                                   float* __restrict__ embn, int n) {
    constexpr int LDK = 136;              // halves; row stride 272 B (16B aligned)
    __shared__ ushort et[128 * LDK];      // ~34 KB emb_f16 tile
    int wid = threadIdx.x >> 6;
    int lane = threadIdx.x & 63;
    int row0 = blockIdx.x * 128 + wid * 32;
    int fr = lane & 15;
    int ko = (lane >> 4) * 8;

    f32x4 acc[2][8];
#pragma unroll
    for (int m = 0; m < 2; m++)
#pragma unroll
        for (int nf = 0; nf < 8; nf++) acc[m][nf] = (f32x4)0.f;

    for (int seg = 0; seg < 2; ++seg) {
        const ushort* A = seg ? A2 : A1;
        const ushort* BT = seg ? B2T : B1T;
#pragma unroll
        for (int k0 = 0; k0 < 128; k0 += 32) {
            f16x8 av[2];
#pragma unroll
            for (int m = 0; m < 2; m++) {
                int row = row0 + m * 16 + fr;
                if (row >= n) row = n - 1;
                av[m] = *reinterpret_cast<const f16x8*>(A + (size_t)row * 128 + k0 + ko);
            }
            f16x8 bv[8];
#pragma unroll
            for (int nf = 0; nf < 8; nf++)
                bv[nf] = *reinterpret_cast<const f16x8*>(BT + (size_t)(nf * 16 + fr) * 128 + k0 + ko);
#pragma unroll
            for (int m = 0; m < 2; m++)
#pragma unroll
                for (int nf = 0; nf < 8; nf++)
                    acc[m][nf] = __builtin_amdgcn_mfma_f32_16x16x32_f16(av[m], bv[nf], acc[m][nf], 0, 0, 0);
        }
    }

    int crow = (lane >> 4) * 4;
    int ccol = lane & 15;
    float bvv[8];
#pragma unroll
    for (int nf = 0; nf < 8; nf++) bvv[nf] = bias[nf * 16 + ccol];

    // bias add, LDS stage, row sum-of-squares (row lives in 16 lanes), emb_n write
#pragma unroll
    for (int m = 0; m < 2; m++) {
#pragma unroll
        for (int reg = 0; reg < 4; reg++) {
            float vv[8];
            float ss = 0.f;
#pragma unroll
            for (int nf = 0; nf < 8; nf++) {
                float v = acc[m][nf][reg] + bvv[nf];
                vv[nf] = v;
                ss += v * v;
            }
            ss += __shfl_xor(ss, 1);
            ss += __shfl_xor(ss, 2);
            ss += __shfl_xor(ss, 4);
            ss += __shfl_xor(ss, 8);
            float inv = 1.0f / fmaxf(sqrtf(ss), 1e-12f);
            int lrow = wid * 32 + m * 16 + crow + reg;
            int grow = blockIdx.x * 128 + lrow;
#pragma unroll
            for (int nf = 0; nf < 8; nf++)
                et[lrow * LDK + nf * 16 + ccol] = f2h(vv[nf]);
            if (grow < n) {
#pragma unroll
                for (int nf = 0; nf < 8; nf++)
                    embn[(size_t)grow * 128 + nf * 16 + ccol] = vv[nf] * inv;
            }
        }
    }
    __syncthreads();

    // out = emb @ Wm + bm (K=128 from LDS, 64 cols)
    f32x4 acc2[2][4];
#pragma unroll
    for (int m = 0; m < 2; m++)
#pragma unroll
        for (int nf = 0; nf < 4; nf++) acc2[m][nf] = (f32x4)0.f;

#pragma unroll
    for (int k0 = 0; k0 < 128; k0 += 32) {
        f16x8 av[2];
#pragma unroll
        for (int m = 0; m < 2; m++) {
            int lrow = wid * 32 + m * 16 + fr;
            av[m] = *reinterpret_cast<const f16x8*>(&et[lrow * LDK + k0 + ko]);
        }
        f16x8 bv[4];
#pragma unroll
        for (int nf = 0; nf < 4; nf++)
            bv[nf] = *reinterpret_cast<const f16x8*>(WmT + (size_t)(nf * 16 + fr) * 128 + k0 + ko);
#pragma unroll
        for (int m = 0; m < 2; m++)
#pragma unroll
            for (int nf = 0; nf < 4; nf++)
                acc2[m][nf] = __builtin_amdgcn_mfma_f32_16x16x32_f16(av[m], bv[nf], acc2[m][nf], 0, 0, 0);
    }

#pragma unroll
    for (int m = 0; m < 2; m++) {
#pragma unroll
        for (int reg = 0; reg < 4; reg++) {
            int grow = row0 + m * 16 + crow + reg;
            if (grow < n) {
#pragma unroll
                for (int nf = 0; nf < 4; nf++)
                    outp[(size_t)grow * 64 + nf * 16 + ccol] = acc2[m][nf][reg] + bm[nf * 16 + ccol];
            }
        }
    }
}

// ---------------- launch ----------------

extern "C" void kernel_launch(void* const* d_in, const int* in_sizes, int n_in,
                              void* d_out, int out_size, void* d_ws, size_t ws_size,
                              hipStream_t stream) {
    const float* x   = (const float*)d_in[0];
    const int*   ei  = (const int*)d_in[1];
    const float* W1l = (const float*)d_in[2];
    const float* b1  = (const float*)d_in[3];
    const float* W1r = (const float*)d_in[4];
    const float* W2l = (const float*)d_in[5];
    const float* b2  = (const float*)d_in[6];
    const float* W2r = (const float*)d_in[7];
    const float* Wm  = (const float*)d_in[8];
    const float* bm  = (const float*)d_in[9];

    const int N = N_NODES, E = N_EDGES;
    const int* src = ei;
    const int* dst = ei + E;

    char* ws = (char*)d_ws;
    int* bcnt  = (int*)ws;  ws += sizeof(int) * NB;
    int* boffs = (int*)ws;  ws += sizeof(int) * NB;
    int* gcur  = (int*)ws;  ws += sizeof(int) * NB;
    uintptr_t p0 = ((uintptr_t)ws + 255) & ~(uintptr_t)255;
    uint* bedges = (uint*)p0;
    uintptr_t p1 = ((uintptr_t)(bedges + N_EDGES) + 255) & ~(uintptr_t)255;
    ushort* mean_f16 = (ushort*)p1;                 // N*128 fp16
    ushort* x_f16    = mean_f16 + (size_t)N * 128;
    ushort* h_f16    = x_f16 + (size_t)N * 128;
    ushort* W1lT     = h_f16 + (size_t)N * 128;     // [128][128] fp16
    ushort* W1rT     = W1lT + 128 * 128;
    ushort* W2lT     = W1rT + 128 * 128;
    ushort* W2rT     = W2lT + 128 * 128;
    ushort* WmT      = W2rT + 128 * 128;            // [64][128] fp16

    float* outp = (float*)d_out;            // N x 64
    float* embn = outp + (size_t)N * 64;    // N x 128 (normalized emb)

    hipMemsetAsync(bcnt, 0, sizeof(int) * NB, stream);
    hipMemsetAsync(gcur, 0, sizeof(int) * NB, stream);

    bucket_count<<<256, 256, 0, stream>>>(dst, bcnt, E);
    scan_buckets<<<1, 256, 0, stream>>>(bcnt, boffs);
    bucket_scatter<<<256, 256, 0, stream>>>(src, dst, boffs, gcur, bedges, E);

    int n4 = N * 128 / 4;
    cast_f32_f16<<<(n4 + 255) / 256, 256, 0, stream>>>(x, x_f16, n4);
    transpose_cast<<<(128 * 128 + 255) / 256, 256, 0, stream>>>(W1l, W1lT, 128, 128);
    transpose_cast<<<(128 * 128 + 255) / 256, 256, 0, stream>>>(W1r, W1rT, 128, 128);
    transpose_cast<<<(128 * 128 + 255) / 256, 256, 0, stream>>>(W2l, W2lT, 128, 128);
    transpose_cast<<<(128 * 128 + 255) / 256, 256, 0, stream>>>(W2r, W2rT, 128, 128);
    transpose_cast<<<(128 * 64 + 255) / 256, 256, 0, stream>>>(Wm, WmT, 128, 64);

    int gblk = (N + 127) / 128;  // 782

    // Layer 1: mean = agg(x_f16); h_f16 = relu(mean@W1l + x@W1r + b1)
    aggregate_bucket<<<NB, 512, 0, stream>>>(x_f16, bedges, boffs, bcnt, mean_f16, N);
    mfma_gemm<true><<<gblk, 256, 0, stream>>>(mean_f16, W1lT, x_f16, W1rT, b1, h_f16, N);

    // Layer 2 fused: mean = agg(h_f16); emb=...; emb_n -> d_out; out = emb@Wm+bm -> d_out
    aggregate_bucket<<<NB, 512, 0, stream>>>(h_f16, bedges, boffs, bcnt, mean_f16, N);
    gemm2_fused<<<gblk, 256, 0, stream>>>(mean_f16, W2lT, h_f16, W2rT, b2,
                                          WmT, bm, outp, embn, N);
}

// Round 9
// 323.700 us; speedup vs baseline: 1.4016x; 1.0431x over previous
//
#include <hip/hip_runtime.h>
#include <hip/hip_fp16.h>
#include <cstdint>
#include <cstddef>

#define N_NODES 100000
#define N_EDGES 1600000
#define BSH 6
#define BNODES 64
#define NB 1563          // ceil(100000/64)
#define CHUNK 2048

typedef _Float16 f16x8 __attribute__((ext_vector_type(8)));
typedef float f32x4 __attribute__((ext_vector_type(4)));

// ---------------- fp16 helpers ----------------

__device__ __forceinline__ float h2f(ushort u) {
    __half_raw r;
    r.x = u;
    return __half2float(__half(r));
}

__device__ __forceinline__ ushort f2h(float f) {
    __half h = __float2half(f);
    return static_cast<__half_raw>(h).x;
}

__device__ __forceinline__ void acc4(float4& a, uint2 v) {
    a.x += h2f((ushort)(v.x & 0xffff));
    a.y += h2f((ushort)(v.x >> 16));
    a.z += h2f((ushort)(v.y & 0xffff));
    a.w += h2f((ushort)(v.y >> 16));
}

// ---------------- fused prep: bucket count + cast x + transpose weights ----------------
// blocks [0,256): bucket histogram; [256, 256+12500): x cast; rest: weight transposes.

__global__ __launch_bounds__(256) void prep_all(
        const int* __restrict__ dst, int* __restrict__ bcnt, int E,
        const float* __restrict__ x, ushort* __restrict__ x_f16, int n4,
        const float* __restrict__ W1l, const float* __restrict__ W1r,
        const float* __restrict__ W2l, const float* __restrict__ W2r,
        const float* __restrict__ Wm,
        ushort* __restrict__ W1lT, ushort* __restrict__ W1rT,
        ushort* __restrict__ W2lT, ushort* __restrict__ W2rT,
        ushort* __restrict__ WmT) {
    int bid = blockIdx.x;
    if (bid < 256) {
        __shared__ int lh[NB];
        for (int i = threadIdx.x; i < NB; i += 256) lh[i] = 0;
        __syncthreads();
        for (int e = bid * 256 + threadIdx.x; e < E; e += 256 * 256)
            atomicAdd(&lh[dst[e] >> BSH], 1);
        __syncthreads();
        for (int i = threadIdx.x; i < NB; i += 256) {
            int v = lh[i];
            if (v) atomicAdd(&bcnt[i], v);
        }
    } else if (bid < 256 + 12500) {
        int i = (bid - 256) * 256 + threadIdx.x;
        if (i < n4) {
            float4 v = reinterpret_cast<const float4*>(x)[i];
            ushort4 o;
            o.x = f2h(v.x);
            o.y = f2h(v.y);
            o.z = f2h(v.z);
            o.w = f2h(v.w);
            reinterpret_cast<ushort4*>(x_f16)[i] = o;
        }
    } else {
        int t = (bid - (256 + 12500)) * 256 + threadIdx.x;
        if (t < 65536) {
            int wsel = t >> 14;
            int r = t & 16383;
            const float* srcs[4] = {W1l, W1r, W2l, W2r};
            ushort* dsts[4] = {W1lT, W1rT, W2lT, W2rT};
            int k = r >> 7, c = r & 127;
            dsts[wsel][c * 128 + k] = f2h(srcs[wsel][r]);
        } else if (t < 65536 + 8192) {
            int r = t - 65536;  // Wm: [128][64]
            int k = r >> 6, c = r & 63;
            WmT[c * 128 + k] = f2h(Wm[r]);
        }
    }
}

// single-block exclusive scan over NB (<= 2048) elements
__global__ void scan_buckets(const int* __restrict__ bcnt, int* __restrict__ boffs) {
    __shared__ int sdata[256];
    int tid = threadIdx.x;
    int v[8];
    int s = 0;
#pragma unroll
    for (int i = 0; i < 8; i++) {
        int idx = tid * 8 + i;
        v[i] = (idx < NB) ? bcnt[idx] : 0;
        s += v[i];
    }
    sdata[tid] = s;
    __syncthreads();
    int acc = s;
    for (int off = 1; off < 256; off <<= 1) {
        int t = (tid >= off) ? sdata[tid - off] : 0;
        __syncthreads();
        acc += t;
        sdata[tid] = acc;
        __syncthreads();
    }
    int excl = acc - s;
#pragma unroll
    for (int i = 0; i < 8; i++) {
        int idx = tid * 8 + i;
        if (idx < NB) boffs[idx] = excl;
        excl += v[i];
    }
}

// scatter edges into bucket regions as packed (dstLocal<<17 | src)
__global__ void bucket_scatter(const int* __restrict__ src, const int* __restrict__ dst,
                               const int* __restrict__ boffs, int* __restrict__ gcur,
                               uint* __restrict__ bedges, int E) {
    __shared__ int lh[NB];
    __shared__ int lbase[NB];
    int nwg = gridDim.x;
    int chunk = (E + nwg - 1) / nwg;
    int e0 = blockIdx.x * chunk;
    int e1 = e0 + chunk;
    if (e1 > E) e1 = E;
    for (int i = threadIdx.x; i < NB; i += 256) lh[i] = 0;
    __syncthreads();
    for (int e = e0 + threadIdx.x; e < e1; e += 256)
        atomicAdd(&lh[dst[e] >> BSH], 1);
    __syncthreads();
    for (int i = threadIdx.x; i < NB; i += 256) {
        int v = lh[i];
        lbase[i] = v ? (boffs[i] + atomicAdd(&gcur[i], v)) : 0;
    }
    __syncthreads();
    for (int i = threadIdx.x; i < NB; i += 256) lh[i] = 0;  // reuse as local cursor
    __syncthreads();
    int e = e0 + threadIdx.x;
#pragma unroll 1
    for (; e + 3 * 256 < e1; e += 4 * 256) {
        int d0 = dst[e + 0 * 256], s0 = src[e + 0 * 256];
        int d1 = dst[e + 1 * 256], s1 = src[e + 1 * 256];
        int d2 = dst[e + 2 * 256], s2 = src[e + 2 * 256];
        int d3 = dst[e + 3 * 256], s3 = src[e + 3 * 256];
        int b0 = d0 >> BSH, b1 = d1 >> BSH, b2 = d2 >> BSH, b3 = d3 >> BSH;
        int r0 = atomicAdd(&lh[b0], 1);
        int r1 = atomicAdd(&lh[b1], 1);
        int r2 = atomicAdd(&lh[b2], 1);
        int r3 = atomicAdd(&lh[b3], 1);
        bedges[lbase[b0] + r0] = ((uint)(d0 & (BNODES - 1)) << 17) | (uint)s0;
        bedges[lbase[b1] + r1] = ((uint)(d1 & (BNODES - 1)) << 17) | (uint)s1;
        bedges[lbase[b2] + r2] = ((uint)(d2 & (BNODES - 1)) << 17) | (uint)s2;
        bedges[lbase[b3] + r3] = ((uint)(d3 & (BNODES - 1)) << 17) | (uint)s3;
    }
    for (; e < e1; e += 256) {
        int d = dst[e];
        int b = d >> BSH;
        int r = atomicAdd(&lh[b], 1);
        bedges[lbase[b] + r] = ((uint)(d & (BNODES - 1)) << 17) | (uint)src[e];
    }
}

// ---------------- bucketed mean aggregation (R7-proven counting-sort version) ----------------
// 512 threads, 8 waves x 8 nodes. Per chunk: LDS counting-sort by dstLocal, then
// wave w owns nodes [w*8, w*8+8); half-wave processes alternating edges (uint2 fp16),
// unroll 4. Cross-half shfl merge at end.

__global__ __launch_bounds__(512) void aggregate_bucket(
        const ushort* __restrict__ F, const uint* __restrict__ bedges,
        const int* __restrict__ boffs, const int* __restrict__ bcnt,
        ushort* __restrict__ out, int n) {
    int b = blockIdx.x;
    int beg = boffs[b];
    int m = bcnt[b];
    int node0 = b << BSH;
    int nNodes = n - node0;
    if (nNodes > BNODES) nNodes = BNODES;
    __shared__ uint ls[CHUNK];
    __shared__ int lh[BNODES];
    __shared__ int lofs[BNODES];
    __shared__ int pcnt[BNODES];
    int tid = threadIdx.x;
    int wid = tid >> 6;     // 0..7
    int lane = tid & 63;
    int hw = lane >> 5;     // half-wave 0/1
    int cl = lane & 31;     // channels cl*4 .. cl*4+3

    float4 acc[8];
#pragma unroll
    for (int i = 0; i < 8; i++) acc[i] = make_float4(0.f, 0.f, 0.f, 0.f);
    if (tid < BNODES) pcnt[tid] = 0;

    for (int base = 0; base < m; base += CHUNK) {
        int mm = m - base;
        if (mm > CHUNK) mm = CHUNK;
        __syncthreads();
        if (tid < BNODES) lh[tid] = 0;
        __syncthreads();
        for (int i = tid; i < mm; i += 512)
            atomicAdd(&lh[bedges[beg + base + i] >> 17], 1);
        __syncthreads();
        if (tid < BNODES) {   // wave 0 only
            int v = lh[tid];
            int s = v;
#pragma unroll
            for (int off = 1; off < 64; off <<= 1) {
                int t = __shfl_up(s, off);
                if (lane >= off) s += t;
            }
            lofs[tid] = s - v;   // exclusive
            pcnt[tid] += v;
            lh[tid] = 0;         // reuse as cursor
        }
        __syncthreads();
        for (int i = tid; i < mm; i += 512) {
            uint p = bedges[beg + base + i];
            int k = p >> 17;
            int r = atomicAdd(&lh[k], 1);
            ls[lofs[k] + r] = p;
        }
        __syncthreads();
#pragma unroll
        for (int ki = 0; ki < 8; ki++) {
            int k = wid * 8 + ki;
            int s0 = lofs[k];
            int ck = lh[k];
            int j = hw;
            for (; j + 6 < ck; j += 8) {
                uint p0 = ls[s0 + j + 0] & 0x1FFFFu;
                uint p1 = ls[s0 + j + 2] & 0x1FFFFu;
                uint p2 = ls[s0 + j + 4] & 0x1FFFFu;
                uint p3 = ls[s0 + j + 6] & 0x1FFFFu;
                uint2 v0 = *reinterpret_cast<const uint2*>(F + (size_t)p0 * 128 + cl * 4);
                uint2 v1 = *reinterpret_cast<const uint2*>(F + (size_t)p1 * 128 + cl * 4);
                uint2 v2 = *reinterpret_cast<const uint2*>(F + (size_t)p2 * 128 + cl * 4);
                uint2 v3 = *reinterpret_cast<const uint2*>(F + (size_t)p3 * 128 + cl * 4);
                acc4(acc[ki], v0);
                acc4(acc[ki], v1);
                acc4(acc[ki], v2);
                acc4(acc[ki], v3);
            }
            for (; j < ck; j += 2) {
                uint p = ls[s0 + j] & 0x1FFFFu;
                uint2 v = *reinterpret_cast<const uint2*>(F + (size_t)p * 128 + cl * 4);
                acc4(acc[ki], v);
            }
        }
    }
    __syncthreads();
#pragma unroll
    for (int ki = 0; ki < 8; ki++) {
        acc[ki].x += __shfl_xor(acc[ki].x, 32);
        acc[ki].y += __shfl_xor(acc[ki].y, 32);
        acc[ki].z += __shfl_xor(acc[ki].z, 32);
        acc[ki].w += __shfl_xor(acc[ki].w, 32);
    }
    if (hw == 0) {
#pragma unroll
        for (int ki = 0; ki < 8; ki++) {
            int k = wid * 8 + ki;
            if (k < nNodes) {
                float inv = 1.0f / fmaxf((float)pcnt[k], 1.0f);
                uint2 o;
                o.x = (uint)f2h(acc[ki].x * inv) | ((uint)f2h(acc[ki].y * inv) << 16);
                o.y = (uint)f2h(acc[ki].z * inv) | ((uint)f2h(acc[ki].w * inv) << 16);
                *reinterpret_cast<uint2*>(out + (size_t)(node0 + k) * 128 + cl * 4) = o;
            }
        }
    }
}

// ---------------- MFMA fp16 GEMM (layer 1), fp16 output only ----------------

template <bool RELU>
__global__ __launch_bounds__(256) void mfma_gemm(const ushort* __restrict__ A1,
                                                 const ushort* __restrict__ B1T,
                                                 const ushort* __restrict__ A2,
                                                 const ushort* __restrict__ B2T,
                                                 const float* __restrict__ bias,
                                                 ushort* __restrict__ Ch, int n) {
    int wid = threadIdx.x >> 6;
    int lane = threadIdx.x & 63;
    int row0 = blockIdx.x * 128 + wid * 32;
    int fr = lane & 15;
    int ko = (lane >> 4) * 8;

    f32x4 acc[2][8];
#pragma unroll
    for (int m = 0; m < 2; m++)
#pragma unroll
        for (int nf = 0; nf < 8; nf++) acc[m][nf] = (f32x4)0.f;

    for (int seg = 0; seg < 2; ++seg) {
        const ushort* A = seg ? A2 : A1;
        const ushort* BT = seg ? B2T : B1T;
#pragma unroll
        for (int k0 = 0; k0 < 128; k0 += 32) {
            f16x8 av[2];
#pragma unroll
            for (int m = 0; m < 2; m++) {
                int row = row0 + m * 16 + fr;
                if (row >= n) row = n - 1;
                av[m] = *reinterpret_cast<const f16x8*>(A + (size_t)row * 128 + k0 + ko);
            }
            f16x8 bv[8];
#pragma unroll
            for (int nf = 0; nf < 8; nf++)
                bv[nf] = *reinterpret_cast<const f16x8*>(BT + (size_t)(nf * 16 + fr) * 128 + k0 + ko);
#pragma unroll
            for (int m = 0; m < 2; m++)
#pragma unroll
                for (int nf = 0; nf < 8; nf++)
                    acc[m][nf] = __builtin_amdgcn_mfma_f32_16x16x32_f16(av[m], bv[nf], acc[m][nf], 0, 0, 0);
        }
    }

    int crow = (lane >> 4) * 4;
    int ccol = lane & 15;
    float bv[8];
#pragma unroll
    for (int nf = 0; nf < 8; nf++) bv[nf] = bias[nf * 16 + ccol];

#pragma unroll
    for (int m = 0; m < 2; m++) {
#pragma unroll
        for (int reg = 0; reg < 4; reg++) {
            int grow = row0 + m * 16 + crow + reg;
            if (grow < n) {
#pragma unroll
                for (int nf = 0; nf < 8; nf++) {
                    float v = acc[m][nf][reg] + bv[nf];
                    if (RELU) v = fmaxf(v, 0.f);
                    Ch[(size_t)grow * 128 + nf * 16 + ccol] = f2h(v);
                }
            }
        }
    }
}

// ---------------- fused layer-2 GEMM + L2-normalize + output GEMM ----------------

__global__ __launch_bounds__(256) void gemm2_fused(const ushort* __restrict__ A1,
                                                   const ushort* __restrict__ B1T,
                                                   const ushort* __restrict__ A2,
                                                   const ushort* __restrict__ B2T,
                                                   const float* __restrict__ bias,
                                                   const ushort* __restrict__ WmT,
                                                   const float* __restrict__ bm,
                                                   float* __restrict__ outp,
                                                   float* __restrict__ embn, int n) {
    constexpr int LDK = 136;              // halves; row stride 272 B (16B aligned)
    __shared__ ushort et[128 * LDK];      // ~34 KB emb_f16 tile
    int wid = threadIdx.x >> 6;
    int lane = threadIdx.x & 63;
    int row0 = blockIdx.x * 128 + wid * 32;
    int fr = lane & 15;
    int ko = (lane >> 4) * 8;

    f32x4 acc[2][8];
#pragma unroll
    for (int m = 0; m < 2; m++)
#pragma unroll
        for (int nf = 0; nf < 8; nf++) acc[m][nf] = (f32x4)0.f;

    for (int seg = 0; seg < 2; ++seg) {
        const ushort* A = seg ? A2 : A1;
        const ushort* BT = seg ? B2T : B1T;
#pragma unroll
        for (int k0 = 0; k0 < 128; k0 += 32) {
            f16x8 av[2];
#pragma unroll
            for (int m = 0; m < 2; m++) {
                int row = row0 + m * 16 + fr;
                if (row >= n) row = n - 1;
                av[m] = *reinterpret_cast<const f16x8*>(A + (size_t)row * 128 + k0 + ko);
            }
            f16x8 bv[8];
#pragma unroll
            for (int nf = 0; nf < 8; nf++)
                bv[nf] = *reinterpret_cast<const f16x8*>(BT + (size_t)(nf * 16 + fr) * 128 + k0 + ko);
#pragma unroll
            for (int m = 0; m < 2; m++)
#pragma unroll
                for (int nf = 0; nf < 8; nf++)
                    acc[m][nf] = __builtin_amdgcn_mfma_f32_16x16x32_f16(av[m], bv[nf], acc[m][nf], 0, 0, 0);
        }
    }

    int crow = (lane >> 4) * 4;
    int ccol = lane & 15;
    float bvv[8];
#pragma unroll
    for (int nf = 0; nf < 8; nf++) bvv[nf] = bias[nf * 16 + ccol];

#pragma unroll
    for (int m = 0; m < 2; m++) {
#pragma unroll
        for (int reg = 0; reg < 4; reg++) {
            float vv[8];
            float ss = 0.f;
#pragma unroll
            for (int nf = 0; nf < 8; nf++) {
                float v = acc[m][nf][reg] + bvv[nf];
                vv[nf] = v;
                ss += v * v;
            }
            ss += __shfl_xor(ss, 1);
            ss += __shfl_xor(ss, 2);
            ss += __shfl_xor(ss, 4);
            ss += __shfl_xor(ss, 8);
            float inv = 1.0f / fmaxf(sqrtf(ss), 1e-12f);
            int lrow = wid * 32 + m * 16 + crow + reg;
            int grow = blockIdx.x * 128 + lrow;
#pragma unroll
            for (int nf = 0; nf < 8; nf++)
                et[lrow * LDK + nf * 16 + ccol] = f2h(vv[nf]);
            if (grow < n) {
#pragma unroll
                for (int nf = 0; nf < 8; nf++)
                    embn[(size_t)grow * 128 + nf * 16 + ccol] = vv[nf] * inv;
            }
        }
    }
    __syncthreads();

    f32x4 acc2[2][4];
#pragma unroll
    for (int m = 0; m < 2; m++)
#pragma unroll
        for (int nf = 0; nf < 4; nf++) acc2[m][nf] = (f32x4)0.f;

#pragma unroll
    for (int k0 = 0; k0 < 128; k0 += 32) {
        f16x8 av[2];
#pragma unroll
        for (int m = 0; m < 2; m++) {
            int lrow = wid * 32 + m * 16 + fr;
            av[m] = *reinterpret_cast<const f16x8*>(&et[lrow * LDK + k0 + ko]);
        }
        f16x8 bv[4];
#pragma unroll
        for (int nf = 0; nf < 4; nf++)
            bv[nf] = *reinterpret_cast<const f16x8*>(WmT + (size_t)(nf * 16 + fr) * 128 + k0 + ko);
#pragma unroll
        for (int m = 0; m < 2; m++)
#pragma unroll
            for (int nf = 0; nf < 4; nf++)
                acc2[m][nf] = __builtin_amdgcn_mfma_f32_16x16x32_f16(av[m], bv[nf], acc2[m][nf], 0, 0, 0);
    }

#pragma unroll
    for (int m = 0; m < 2; m++) {
#pragma unroll
        for (int reg = 0; reg < 4; reg++) {
            int grow = row0 + m * 16 + crow + reg;
            if (grow < n) {
#pragma unroll
                for (int nf = 0; nf < 4; nf++)
                    outp[(size_t)grow * 64 + nf * 16 + ccol] = acc2[m][nf][reg] + bm[nf * 16 + ccol];
            }
        }
    }
}

// ---------------- launch ----------------

extern "C" void kernel_launch(void* const* d_in, const int* in_sizes, int n_in,
                              void* d_out, int out_size, void* d_ws, size_t ws_size,
                              hipStream_t stream) {
    const float* x   = (const float*)d_in[0];
    const int*   ei  = (const int*)d_in[1];
    const float* W1l = (const float*)d_in[2];
    const float* b1  = (const float*)d_in[3];
    const float* W1r = (const float*)d_in[4];
    const float* W2l = (const float*)d_in[5];
    const float* b2  = (const float*)d_in[6];
    const float* W2r = (const float*)d_in[7];
    const float* Wm  = (const float*)d_in[8];
    const float* bm  = (const float*)d_in[9];

    const int N = N_NODES, E = N_EDGES;
    const int* src = ei;
    const int* dst = ei + E;

    char* ws = (char*)d_ws;
    int* bcnt  = (int*)ws;  ws += sizeof(int) * NB;
    int* boffs = (int*)ws;  ws += sizeof(int) * NB;
    int* gcur  = (int*)ws;  ws += sizeof(int) * NB;
    uintptr_t p0 = ((uintptr_t)ws + 255) & ~(uintptr_t)255;
    uint* bedges = (uint*)p0;
    uintptr_t p1 = ((uintptr_t)(bedges + N_EDGES) + 255) & ~(uintptr_t)255;
    ushort* mean_f16 = (ushort*)p1;                 // N*128 fp16
    ushort* x_f16    = mean_f16 + (size_t)N * 128;
    ushort* h_f16    = x_f16 + (size_t)N * 128;
    ushort* W1lT     = h_f16 + (size_t)N * 128;     // [128][128] fp16
    ushort* W1rT     = W1lT + 128 * 128;
    ushort* W2lT     = W1rT + 128 * 128;
    ushort* W2rT     = W2lT + 128 * 128;
    ushort* WmT      = W2rT + 128 * 128;            // [64][128] fp16

    float* outp = (float*)d_out;            // N x 64
    float* embn = outp + (size_t)N * 64;    // N x 128 (normalized emb)

    hipMemsetAsync(bcnt, 0, sizeof(int) * NB, stream);
    hipMemsetAsync(gcur, 0, sizeof(int) * NB, stream);

    int n4 = N * 128 / 4;                           // 3,200,000
    int prep_blocks = 256 + 12500 + 288;
    prep_all<<<prep_blocks, 256, 0, stream>>>(dst, bcnt, E, x, x_f16, n4,
                                              W1l, W1r, W2l, W2r, Wm,
                                              W1lT, W1rT, W2lT, W2rT, WmT);
    scan_buckets<<<1, 256, 0, stream>>>(bcnt, boffs);
    bucket_scatter<<<256, 256, 0, stream>>>(src, dst, boffs, gcur, bedges, E);

    int gblk = (N + 127) / 128;  // 782

    // Layer 1: mean = agg(x_f16); h_f16 = relu(mean@W1l + x@W1r + b1)
    aggregate_bucket<<<NB, 512, 0, stream>>>(x_f16, bedges, boffs, bcnt, mean_f16, N);
    mfma_gemm<true><<<gblk, 256, 0, stream>>>(mean_f16, W1lT, x_f16, W1rT, b1, h_f16, N);

    // Layer 2 fused: mean = agg(h_f16); emb_n -> d_out; out = emb@Wm+bm -> d_out
    aggregate_bucket<<<NB, 512, 0, stream>>>(h_f16, bedges, boffs, bcnt, mean_f16, N);
    gemm2_fused<<<gblk, 256, 0, stream>>>(mean_f16, W2lT, h_f16, W2rT, b2,
                                          WmT, bm, outp, embn, N);
}